// Round 9
// baseline (376.766 us; speedup 1.0000x reference)
//
#include <hip/hip_runtime.h>

#define D 128
#define TWO_D 256
#define BN_EPS 1e-5f

typedef __attribute__((ext_vector_type(8))) short bf16x8;   // 8 bf16 = 4 VGPR
typedef __attribute__((ext_vector_type(4))) float f32x4;

__device__ __forceinline__ float relu_f(float x) { return x > 0.f ? x : 0.f; }

__device__ __forceinline__ unsigned short f2bf(float f) {   // RTN-even
    unsigned u = __builtin_bit_cast(unsigned, f);
    return (unsigned short)((u + 0x7FFFu + ((u >> 16) & 1u)) >> 16);
}
__device__ __forceinline__ float bf2f(unsigned s) {
    unsigned u = s << 16;
    return __builtin_bit_cast(float, u);
}
__device__ __forceinline__ unsigned pack2(float a, float b) {
    return (unsigned)f2bf(a) | ((unsigned)f2bf(b) << 16);
}

// h[n][d] = bf16(atom_emb0[x0][d] + atom_emb1[x1][d]); zeroes pad row + statsA
__global__ void atom_embed_kernel(const int* __restrict__ x,
                                  const float* __restrict__ emb0,
                                  const float* __restrict__ emb1,
                                  unsigned short* __restrict__ hbf,
                                  float* __restrict__ statsA, int n) {
    if (blockIdx.x == 0) {
        if (threadIdx.x < 64)
            reinterpret_cast<unsigned*>(hbf + (size_t)n * D)[threadIdx.x] = 0u;
        statsA[threadIdx.x] = 0.f;      // 256 floats
    }
    int idx = blockIdx.x * blockDim.x + threadIdx.x;
    if (idx >= n * 32) return;
    int node = idx >> 5;
    int d0 = (idx & 31) << 2;
    int i0 = x[node * 2 + 0];
    int i1 = x[node * 2 + 1];
    const float4 a = *reinterpret_cast<const float4*>(emb0 + (size_t)i0 * D + d0);
    const float4 b = *reinterpret_cast<const float4*>(emb1 + (size_t)i1 * D + d0);
    uint2 v;
    v.x = pack2(a.x + b.x, a.y + b.y);
    v.y = pack2(a.z + b.z, a.w + b.w);
    *reinterpret_cast<uint2*>(hbf + (size_t)node * D + d0) = v;
}

// ---- CSR build (once per launch) ----
__global__ void hist_kernel(const int* __restrict__ ei, int* __restrict__ counts, int e_cnt) {
    int e = blockIdx.x * blockDim.x + threadIdx.x;
    if (e >= e_cnt) return;
    atomicAdd(counts + ei[e_cnt + e], 1);
}

__device__ __forceinline__ int pad8(int d) { return (d + 7) & ~7; }

__global__ __launch_bounds__(256) void bsum_kernel(const int* __restrict__ counts,
                                                   int* __restrict__ bsum, int n) {
    __shared__ int s[256];
    int t = threadIdx.x;
    int idx = blockIdx.x * 256 + t;
    s[t] = (idx < n) ? pad8(counts[idx]) : 0;
    __syncthreads();
    for (int off = 128; off > 0; off >>= 1) {
        if (t < off) s[t] += s[t + off];
        __syncthreads();
    }
    if (t == 0) bsum[blockIdx.x] = s[0];
}

__global__ __launch_bounds__(256) void bscan_kernel(const int* __restrict__ bsum,
                                                    int* __restrict__ bpre,
                                                    int* __restrict__ rpp, int nb, int n) {
    __shared__ int s[256];
    int t = threadIdx.x;
    s[t] = (t < nb) ? bsum[t] : 0;
    __syncthreads();
    for (int off = 1; off < 256; off <<= 1) {
        int v = (t >= off) ? s[t - off] : 0;
        __syncthreads();
        s[t] += v;
        __syncthreads();
    }
    bpre[t] = (t == 0) ? 0 : s[t - 1];
    if (t == 255) rpp[n] = s[255];
}

__global__ __launch_bounds__(256) void scan_apply_kernel(const int* __restrict__ counts,
                                                         const int* __restrict__ bpre,
                                                         int* __restrict__ rpp,
                                                         int* __restrict__ cursor, int n) {
    __shared__ int s[256];
    int t = threadIdx.x;
    int idx = blockIdx.x * 256 + t;
    int c = (idx < n) ? pad8(counts[idx]) : 0;
    s[t] = c;
    __syncthreads();
    for (int off = 1; off < 256; off <<= 1) {
        int v = (t >= off) ? s[t - off] : 0;
        __syncthreads();
        s[t] += v;
        __syncthreads();
    }
    if (idx < n) {
        int excl = bpre[blockIdx.x] + s[t] - c;
        rpp[idx] = excl;
        cursor[idx] = excl;
    }
}

// edge fill: u16 src + u8 aidx at the same cursor slot
__global__ void fill_kernel(const int* __restrict__ ei, const int* __restrict__ ea,
                            int* __restrict__ cursor,
                            unsigned short* __restrict__ ep,
                            unsigned char* __restrict__ eaidx, int e_cnt) {
    int e = blockIdx.x * blockDim.x + threadIdx.x;
    if (e >= e_cnt) return;
    int dst = ei[e_cnt + e];
    int src = ei[e];
    int aidx = ea[e * 2 + 0] * 3 + ea[e * 2 + 1];   // [0,9)
    int pos = atomicAdd(cursor + dst, 1);
    ep[pos] = (unsigned short)src;
    eaidx[pos] = (unsigned char)aidx;
}

// pad each node's list to multiple of 8: ep with zero-row index, eaidx with 9
__global__ void pad_kernel(const int* __restrict__ cursor, const int* __restrict__ counts,
                           const int* __restrict__ rpp,
                           unsigned short* __restrict__ ep,
                           unsigned char* __restrict__ eaidx, int n) {
    int i = blockIdx.x * blockDim.x + threadIdx.x;
    if (i >= n) return;
    int b = cursor[i];                       // rpp[i] + deg
    int e = rpp[i] + pad8(counts[i]);
    unsigned short zr = (unsigned short)n;
    for (int j = b; j < e; ++j) { ep[j] = zr; eaidx[j] = 9; }
}

// per-node packed aidx byte-counters, NO atomics
__global__ void cnts_build_kernel(const int* __restrict__ rpp,
                                  const int* __restrict__ counts,
                                  const unsigned char* __restrict__ eaidx,
                                  unsigned long long* __restrict__ cnts, int n) {
    int i = blockIdx.x * blockDim.x + threadIdx.x;
    if (i >= n) return;
    const int jb = rpp[i];                   // multiple of 8
    const int nch = pad8(counts[i]) >> 3;
    unsigned long long c = 0ull;
    for (int ch = 0; ch < nch; ++ch) {
        unsigned long long v = *reinterpret_cast<const unsigned long long*>(eaidx + jb + 8 * ch);
        #pragma unroll
        for (int b = 0; b < 8; ++b) {
            int a = (int)((v >> (b * 8)) & 0xFFull);
            if (a < 8) c += 1ull << (a * 8);
        }
    }
    cnts[i] = c;
}

// ---- weight fragment pre-pack (bf16, per-lane MFMA B-operand layout) ----
__global__ void frag_prep_kernel(const float* __restrict__ W1,
                                 const float* __restrict__ W2,
                                 unsigned short* __restrict__ w1f,
                                 unsigned short* __restrict__ w2f, int Lnum) {
    int tid = blockIdx.x * blockDim.x + threadIdx.x;
    if (tid >= Lnum * 128 * 64) return;
    int l = tid / 8192;
    int rem = tid % 8192;
    int frag = rem / 64;
    int lane = rem % 64;
    int kg = lane >> 4, cl = lane & 15;
    if (frag < 64) {
        int kk = frag >> 4, tn = frag & 15;
        const float* src = W1 + (size_t)l * D * TWO_D;
        int k0 = kk * 32 + kg * 8, col = tn * 16 + cl;
        unsigned short* dst = w1f + (size_t)l * 32768 + ((size_t)frag * 64 + lane) * 8;
        #pragma unroll
        for (int j = 0; j < 8; ++j) dst[j] = f2bf(src[(size_t)(k0 + j) * TWO_D + col]);
    } else {
        int f2 = frag - 64;
        int kk = f2 >> 3, tn = f2 & 7;
        const float* src = W2 + (size_t)l * TWO_D * D;
        int k0 = kk * 32 + kg * 8, col = tn * 16 + cl;
        unsigned short* dst = w2f + (size_t)l * 32768 + ((size_t)f2 * 64 + lane) * 8;
        #pragma unroll
        for (int j = 0; j < 8; ++j) dst[j] = f2bf(src[(size_t)(k0 + j) * D + col]);
    }
}

// ---- FUSED per-layer kernel: gather(32 rows -> LDS) + MLP MFMA + BN stats ----
// Persistent blocks grid-stride over 32-row pairs. Gather overlaps other
// blocks' MFMA on the same CU (separate pipes). W frags reloaded from L2-hot
// w1f/w2f each pair (issued before barriers) to keep VGPRs low.
__global__ __launch_bounds__(256) void fused_layer_kernel(
    const unsigned short* __restrict__ hbf,
    const float* __restrict__ ee0_l, const float* __restrict__ ee1_l,
    const int* __restrict__ rpp, const int* __restrict__ counts,
    const unsigned long long* __restrict__ cnts,
    const unsigned short* __restrict__ ep,
    const bf16x8* __restrict__ w1f, const bf16x8* __restrict__ w2f,
    const float* __restrict__ b1l, const float* __restrict__ b2l,
    float* __restrict__ outf, float* __restrict__ stats, int n) {

    __shared__ float cee[16 * D];                 // 8 KB
    __shared__ unsigned short agg[32 * D];        // 8 KB, XOR-swizzled rows
    __shared__ unsigned short hid[32 * TWO_D];    // 16 KB, XOR-swizzled
    __shared__ float sred[256];

    const int t = threadIdx.x;
    for (int i = t; i < 16 * D; i += 256) {
        int r = i >> 7, d = i & 127;
        cee[i] = (r < 15) ? ee0_l[(r / 3) * D + d] + ee1_l[(r % 3) * D + d]
                          : ee0_l[4 * D + d] + ee1_l[d];
    }

    const int wave = t >> 6;
    const int lane = t & 63;
    const int arow = lane & 15;
    const int kgrp = lane >> 4;
    const int hw = t >> 5;           // half-wave 0..7 (gather node slot)
    const int d0 = (t & 31) << 2;    // gather column

    float b1v[4], b2v[2];
    #pragma unroll
    for (int tt = 0; tt < 4; ++tt) b1v[tt] = b1l[wave * 64 + tt * 16 + arow];
    #pragma unroll
    for (int tt = 0; tt < 2; ++tt) b2v[tt] = b2l[wave * 32 + tt * 16 + arow];

    __syncthreads();   // cee ready

    float ps[2] = {0.f, 0.f}, pq[2] = {0.f, 0.f};

    const int tiles = n >> 4;            // n % 16 == 0
    const int npair = (tiles + 1) >> 1;

    for (int p = blockIdx.x; p < npair; p += gridDim.x) {
        const int row0 = p << 5;
        const bool has1 = (row0 + 16 < n);

        // ---- gather phase: 4 subpasses x 8 half-waves -> 32 rows in agg ----
        #pragma unroll 1
        for (int s = 0; s < 4; ++s) {
            const int nl = s * 8 + hw;
            const int node = row0 + nl;
            if (node < n) {
                const int jb = rpp[node];
                const int deg = counts[node];
                const unsigned long long c0 = cnts[node];
                const int nch = pad8(deg) >> 3;

                float ax, ay, az, aw;
                {
                    const float4 cs = *reinterpret_cast<const float4*>(cee + 15 * D + d0);
                    uint2 hv = *reinterpret_cast<const uint2*>(hbf + (size_t)node * D + d0);
                    ax = bf2f(hv.x & 0xffffu) + cs.x;
                    ay = bf2f(hv.x >> 16)     + cs.y;
                    az = bf2f(hv.y & 0xffffu) + cs.z;
                    aw = bf2f(hv.y >> 16)     + cs.w;
                }
                int csum = 0;
                #pragma unroll
                for (int a = 0; a < 8; ++a) {
                    int fc = (int)((c0 >> (a * 8)) & 0xFFull);
                    csum += fc;
                    float f = (float)fc;
                    const float4 ev = *reinterpret_cast<const float4*>(cee + a * D + d0);
                    ax += f * ev.x; ay += f * ev.y; az += f * ev.z; aw += f * ev.w;
                }
                {
                    float f = (float)(deg - csum);
                    const float4 ev = *reinterpret_cast<const float4*>(cee + 8 * D + d0);
                    ax += f * ev.x; ay += f * ev.y; az += f * ev.z; aw += f * ev.w;
                }

#define ROWLD(s_) (*reinterpret_cast<const uint2*>(hbf + (size_t)(s_) * D + d0))
#define EACC(sv) do { \
        ax += bf2f((sv).x & 0xffffu); ay += bf2f((sv).x >> 16); \
        az += bf2f((sv).y & 0xffffu); aw += bf2f((sv).y >> 16); } while (0)
#define PROC(iv) do { \
        const uint2 s0 = ROWLD((iv).x & 0xFFFFu), s1 = ROWLD((iv).x >> 16); \
        const uint2 s2 = ROWLD((iv).y & 0xFFFFu), s3 = ROWLD((iv).y >> 16); \
        const uint2 s4 = ROWLD((iv).z & 0xFFFFu), s5 = ROWLD((iv).z >> 16); \
        const uint2 s6 = ROWLD((iv).w & 0xFFFFu), s7 = ROWLD((iv).w >> 16); \
        EACC(s0); EACC(s1); EACC(s2); EACC(s3); \
        EACC(s4); EACC(s5); EACC(s6); EACC(s7); } while (0)
                if (nch) {
                    uint4 iv = *reinterpret_cast<const uint4*>(ep + jb);
                    for (int c = 1; c < nch; ++c) {
                        uint4 nx = *reinterpret_cast<const uint4*>(ep + jb + 8 * c);
                        PROC(iv);
                        iv = nx;
                    }
                    PROC(iv);
                }
#undef ROWLD
#undef EACC
#undef PROC
                uint2 o;
                o.x = pack2(ax, ay);
                o.y = pack2(az, aw);
                *reinterpret_cast<uint2*>(agg + ((nl * D + d0) ^ ((nl & 7) << 3))) = o;
            }
        }

        // issue W1 frag loads before the barrier (latency hides under wait)
        bf16x8 W1f[4][4];
        #pragma unroll
        for (int kk = 0; kk < 4; ++kk)
            #pragma unroll
            for (int tt = 0; tt < 4; ++tt)
                W1f[kk][tt] = w1f[(kk * 16 + wave * 4 + tt) * 64 + lane];

        __syncthreads();   // agg ready; prev-iter hid reads complete

        // ---- MFMA phase ----
        bf16x8 a0[4], a1[4];
        #pragma unroll
        for (int kk = 0; kk < 4; ++kk)
            a0[kk] = *reinterpret_cast<const bf16x8*>(
                agg + ((arow * D + kk * 32 + kgrp * 8) ^ ((arow & 7) << 3)));
        if (has1) {
            #pragma unroll
            for (int kk = 0; kk < 4; ++kk)
                a1[kk] = *reinterpret_cast<const bf16x8*>(
                    agg + (((16 + arow) * D + kk * 32 + kgrp * 8) ^ ((arow & 7) << 3)));
        }

        f32x4 acc1[4];
        #pragma unroll
        for (int tt = 0; tt < 4; ++tt) acc1[tt] = (f32x4){0.f, 0.f, 0.f, 0.f};
        #pragma unroll
        for (int kk = 0; kk < 4; ++kk)
            #pragma unroll
            for (int tt = 0; tt < 4; ++tt)
                acc1[tt] = __builtin_amdgcn_mfma_f32_16x16x32_bf16(a0[kk], W1f[kk][tt], acc1[tt], 0, 0, 0);
        #pragma unroll
        for (int tt = 0; tt < 4; ++tt) {
            const int cc = wave * 64 + tt * 16 + arow;
            #pragma unroll
            for (int r = 0; r < 4; ++r) {
                const int rr = kgrp * 4 + r;
                hid[(rr * TWO_D + cc) ^ ((rr & 7) << 3)] = f2bf(relu_f(acc1[tt][r] + b1v[tt]));
            }
        }
        if (has1) {
            #pragma unroll
            for (int tt = 0; tt < 4; ++tt) acc1[tt] = (f32x4){0.f, 0.f, 0.f, 0.f};
            #pragma unroll
            for (int kk = 0; kk < 4; ++kk)
                #pragma unroll
                for (int tt = 0; tt < 4; ++tt)
                    acc1[tt] = __builtin_amdgcn_mfma_f32_16x16x32_bf16(a1[kk], W1f[kk][tt], acc1[tt], 0, 0, 0);
            #pragma unroll
            for (int tt = 0; tt < 4; ++tt) {
                const int cc = wave * 64 + tt * 16 + arow;
                #pragma unroll
                for (int r = 0; r < 4; ++r) {
                    const int rr = 16 + kgrp * 4 + r;
                    hid[(rr * TWO_D + cc) ^ ((rr & 7) << 3)] = f2bf(relu_f(acc1[tt][r] + b1v[tt]));
                }
            }
        }

        // issue W2 frag loads before the barrier
        bf16x8 W2f[8][2];
        #pragma unroll
        for (int kk = 0; kk < 8; ++kk)
            #pragma unroll
            for (int tt = 0; tt < 2; ++tt)
                W2f[kk][tt] = w2f[(kk * 8 + wave * 2 + tt) * 64 + lane];

        __syncthreads();   // hid ready

        {
            f32x4 acc2[2];
            #pragma unroll
            for (int tt = 0; tt < 2; ++tt) acc2[tt] = (f32x4){0.f, 0.f, 0.f, 0.f};
            #pragma unroll
            for (int kk = 0; kk < 8; ++kk) {
                bf16x8 a2 = *reinterpret_cast<const bf16x8*>(
                    hid + ((arow * TWO_D + kk * 32 + kgrp * 8) ^ ((arow & 7) << 3)));
                #pragma unroll
                for (int tt = 0; tt < 2; ++tt)
                    acc2[tt] = __builtin_amdgcn_mfma_f32_16x16x32_bf16(a2, W2f[kk][tt], acc2[tt], 0, 0, 0);
            }
            #pragma unroll
            for (int tt = 0; tt < 2; ++tt) {
                const int col = wave * 32 + tt * 16 + arow;
                #pragma unroll
                for (int r = 0; r < 4; ++r) {
                    float v = acc2[tt][r] + b2v[tt];
                    outf[((size_t)row0 + kgrp * 4 + r) * D + col] = v;
                    ps[tt] += v; pq[tt] += v * v;
                }
            }
        }
        if (has1) {
            f32x4 acc2[2];
            #pragma unroll
            for (int tt = 0; tt < 2; ++tt) acc2[tt] = (f32x4){0.f, 0.f, 0.f, 0.f};
            #pragma unroll
            for (int kk = 0; kk < 8; ++kk) {
                bf16x8 a2 = *reinterpret_cast<const bf16x8*>(
                    hid + (((16 + arow) * TWO_D + kk * 32 + kgrp * 8) ^ ((arow & 7) << 3)));
                #pragma unroll
                for (int tt = 0; tt < 2; ++tt)
                    acc2[tt] = __builtin_amdgcn_mfma_f32_16x16x32_bf16(a2, W2f[kk][tt], acc2[tt], 0, 0, 0);
            }
            #pragma unroll
            for (int tt = 0; tt < 2; ++tt) {
                const int col = wave * 32 + tt * 16 + arow;
                #pragma unroll
                for (int r = 0; r < 4; ++r) {
                    float v = acc2[tt][r] + b2v[tt];
                    outf[((size_t)row0 + 16 + kgrp * 4 + r) * D + col] = v;
                    ps[tt] += v; pq[tt] += v * v;
                }
            }
        }
    }

    sred[t] = 0.f;
    __syncthreads();
    #pragma unroll
    for (int tt = 0; tt < 2; ++tt) {
        const int col = wave * 32 + tt * 16 + arow;
        atomicAdd(sred + col, ps[tt]);
        atomicAdd(sred + 128 + col, pq[tt]);
    }
    __syncthreads();
    unsafeAtomicAdd(stats + t, sred[t]);
}

// mid layers: h_next = bf16(relu(out*sc+sh)); zeroes pad row + next stats buf
__global__ void bn_mid_kernel(const float* __restrict__ out,
                              const float* __restrict__ stats,
                              float* __restrict__ stats_next,
                              const float* __restrict__ gamma_l,
                              const float* __restrict__ beta_l,
                              float inv_n,
                              unsigned short* __restrict__ dsth, int n) {
    __shared__ float sbn[2 * D];
    int t = threadIdx.x;
    if (blockIdx.x == 0) {
        stats_next[t] = 0.f;
        if (t >= 128 && t < 192)
            reinterpret_cast<unsigned*>(dsth + (size_t)n * D)[t - 128] = 0u;
    }
    if (t < 128) {
        float mean = stats[t] * inv_n;
        float var  = stats[128 + t] * inv_n - mean * mean;
        float sc = gamma_l[t] * rsqrtf(var + BN_EPS);
        sbn[t] = sc;
        sbn[128 + t] = beta_l[t] - mean * sc;
    }
    __syncthreads();
    int idx = blockIdx.x * blockDim.x + t;
    if (idx >= n * 32) return;
    int d0 = (idx & 31) << 2;
    float4 v  = *reinterpret_cast<const float4*>(out + (size_t)idx * 4);
    float4 sc = *reinterpret_cast<const float4*>(sbn + d0);
    float4 sh = *reinterpret_cast<const float4*>(sbn + 128 + d0);
    uint2 o;
    o.x = pack2(relu_f(v.x * sc.x + sh.x), relu_f(v.y * sc.y + sh.y));
    o.y = pack2(relu_f(v.z * sc.z + sh.z), relu_f(v.w * sc.w + sh.w));
    *reinterpret_cast<uint2*>(dsth + (size_t)idx * 4) = o;
}

// final: d_out = out*sc+sh (f32, no relu)
__global__ void bn_apply_final_kernel(const float* __restrict__ out,
                                      const float* __restrict__ stats,
                                      const float* __restrict__ gamma_l,
                                      const float* __restrict__ beta_l,
                                      float inv_n,
                                      float* __restrict__ dst, int n) {
    __shared__ float sbn[2 * D];
    int t = threadIdx.x;
    if (t < 128) {
        float mean = stats[t] * inv_n;
        float var  = stats[128 + t] * inv_n - mean * mean;
        float sc = gamma_l[t] * rsqrtf(var + BN_EPS);
        sbn[t] = sc;
        sbn[128 + t] = beta_l[t] - mean * sc;
    }
    __syncthreads();
    int idx = blockIdx.x * blockDim.x + t;
    if (idx >= n * 32) return;
    int d0 = (idx & 31) << 2;
    float4 v  = *reinterpret_cast<const float4*>(out + (size_t)idx * 4);
    float4 sc = *reinterpret_cast<const float4*>(sbn + d0);
    float4 sh = *reinterpret_cast<const float4*>(sbn + 128 + d0);
    *reinterpret_cast<float4*>(dst + (size_t)idx * 4) =
        make_float4(v.x * sc.x + sh.x, v.y * sc.y + sh.y,
                    v.z * sc.z + sh.z, v.w * sc.w + sh.w);
}

extern "C" void kernel_launch(void* const* d_in, const int* in_sizes, int n_in,
                              void* d_out, int out_size, void* d_ws, size_t ws_size,
                              hipStream_t stream) {
    const int*   x     = (const int*)d_in[0];
    const int*   ei    = (const int*)d_in[1];
    const int*   ea    = (const int*)d_in[2];
    const float* aemb0 = (const float*)d_in[3];
    const float* aemb1 = (const float*)d_in[4];
    const float* eemb0 = (const float*)d_in[5];
    const float* eemb1 = (const float*)d_in[6];
    const float* W1    = (const float*)d_in[7];
    const float* b1    = (const float*)d_in[8];
    const float* W2    = (const float*)d_in[9];
    const float* b2    = (const float*)d_in[10];
    const float* gamma = (const float*)d_in[11];
    const float* beta  = (const float*)d_in[12];

    const int n = in_sizes[0] / 2;          // 50000
    const int e = in_sizes[1] / 2;          // 500000
    const int L = in_sizes[8] / TWO_D;      // 3
    const float inv_n = 1.0f / (float)n;

    char* ws = (char*)d_ws;
    float* outb = (float*)ws;                      ws += (size_t)n * D * 4;
    unsigned short* buf0 = (unsigned short*)ws;    ws += (size_t)(n + 1) * D * 2;
    unsigned short* buf1 = (unsigned short*)ws;    ws += (size_t)(n + 1) * D * 2;
    unsigned short* w1f = (unsigned short*)ws;     ws += (size_t)L * 32768 * 2;
    unsigned short* w2f = (unsigned short*)ws;     ws += (size_t)L * 32768 * 2;
    float* statsA = (float*)ws;                    ws += 256 * 4;
    float* statsB = (float*)ws;                    ws += 256 * 4;
    int* counts  = (int*)ws;                       ws += (size_t)n * 4;
    unsigned long long* cnts = (unsigned long long*)ws;  ws += (size_t)n * 8;
    int* rpp     = (int*)ws;                       ws += (size_t)(n + 4) * 4;
    int* cursor  = (int*)ws;                       ws += (size_t)n * 4;
    int* bsum    = (int*)ws;                       ws += 256 * 4;
    int* bpre    = (int*)ws;                       ws += 256 * 4;
    unsigned short* epack = (unsigned short*)ws;   ws += ((size_t)e + 8 * (size_t)n) * 2;
    unsigned char* eaidx  = (unsigned char*)ws;    // padded u8 aidx

    const int edge_blocks = (e + 255) / 256;
    const int vec_blocks  = (n * 32 + 255) / 256;
    const int nb = (n + 255) / 256;          // 196 <= 256

    hipMemsetAsync(counts, 0, (size_t)n * 4, stream);
    hist_kernel<<<edge_blocks, 256, 0, stream>>>(ei, counts, e);
    bsum_kernel<<<nb, 256, 0, stream>>>(counts, bsum, n);
    bscan_kernel<<<1, 256, 0, stream>>>(bsum, bpre, rpp, nb, n);
    scan_apply_kernel<<<nb, 256, 0, stream>>>(counts, bpre, rpp, cursor, n);
    fill_kernel<<<edge_blocks, 256, 0, stream>>>(ei, ea, cursor, epack, eaidx, e);
    pad_kernel<<<nb, 256, 0, stream>>>(cursor, counts, rpp, epack, eaidx, n);
    cnts_build_kernel<<<nb, 256, 0, stream>>>(rpp, counts, eaidx, cnts, n);
    frag_prep_kernel<<<(L * 128 * 64 + 255) / 256, 256, 0, stream>>>(W1, W2, w1f, w2f, L);
    atom_embed_kernel<<<vec_blocks, 256, 0, stream>>>(x, aemb0, aemb1, buf0, statsA, n);

    for (int l = 0; l < L; ++l) {
        const float* ee0_l = eemb0 + (size_t)l * 5 * D;
        const float* ee1_l = eemb1 + (size_t)l * 3 * D;

        unsigned short* hsrc = (l & 1) ? buf1 : buf0;
        float* stats_cur  = (l & 1) ? statsB : statsA;
        float* stats_next = (l & 1) ? statsA : statsB;

        fused_layer_kernel<<<512, 256, 0, stream>>>(
            hsrc, ee0_l, ee1_l, rpp, counts, cnts, epack,
            (const bf16x8*)(w1f + (size_t)l * 32768),
            (const bf16x8*)(w2f + (size_t)l * 32768),
            b1 + (size_t)l * TWO_D, b2 + (size_t)l * D,
            outb, stats_cur, n);

        if (l < L - 1) {
            unsigned short* hdst = (l & 1) ? buf0 : buf1;
            bn_mid_kernel<<<vec_blocks, 256, 0, stream>>>(
                outb, stats_cur, stats_next, gamma + (size_t)l * D, beta + (size_t)l * D,
                inv_n, hdst, n);
        } else {
            bn_apply_final_kernel<<<vec_blocks, 256, 0, stream>>>(
                outb, stats_cur, gamma + (size_t)l * D, beta + (size_t)l * D,
                inv_n, (float*)d_out, n);
        }
    }
}

// Round 10
// 268.312 us; speedup vs baseline: 1.4042x; 1.4042x over previous
//
#include <hip/hip_runtime.h>

#define D 128
#define TWO_D 256
#define BN_EPS 1e-5f

typedef __attribute__((ext_vector_type(8))) short bf16x8;   // 8 bf16 = 4 VGPR
typedef __attribute__((ext_vector_type(4))) float f32x4;

__device__ __forceinline__ float relu_f(float x) { return x > 0.f ? x : 0.f; }

__device__ __forceinline__ unsigned short f2bf(float f) {   // RTN-even
    unsigned u = __builtin_bit_cast(unsigned, f);
    return (unsigned short)((u + 0x7FFFu + ((u >> 16) & 1u)) >> 16);
}
__device__ __forceinline__ float bf2f(unsigned s) {
    unsigned u = s << 16;
    return __builtin_bit_cast(float, u);
}
__device__ __forceinline__ unsigned pack2(float a, float b) {
    return (unsigned)f2bf(a) | ((unsigned)f2bf(b) << 16);
}

__device__ __forceinline__ int pad8(int d) { return (d + 7) & ~7; }

// h = bf16(emb0[x0]+emb1[x1]); zeroes pad row n of BOTH ping-pong buffers
__global__ void atom_embed_kernel(const int* __restrict__ x,
                                  const float* __restrict__ emb0,
                                  const float* __restrict__ emb1,
                                  unsigned short* __restrict__ bufA,
                                  unsigned short* __restrict__ bufB, int n) {
    if (blockIdx.x == 0 && threadIdx.x < 64)
        reinterpret_cast<unsigned*>(bufA + (size_t)n * D)[threadIdx.x] = 0u;
    if (blockIdx.x == 1 && threadIdx.x < 64)
        reinterpret_cast<unsigned*>(bufB + (size_t)n * D)[threadIdx.x] = 0u;
    int idx = blockIdx.x * blockDim.x + threadIdx.x;
    if (idx >= n * 32) return;
    int node = idx >> 5;
    int d0 = (idx & 31) << 2;
    int i0 = x[node * 2 + 0];
    int i1 = x[node * 2 + 1];
    const float4 a = *reinterpret_cast<const float4*>(emb0 + (size_t)i0 * D + d0);
    const float4 b = *reinterpret_cast<const float4*>(emb1 + (size_t)i1 * D + d0);
    uint2 v;
    v.x = pack2(a.x + b.x, a.y + b.y);
    v.y = pack2(a.z + b.z, a.w + b.w);
    *reinterpret_cast<uint2*>(bufA + (size_t)node * D + d0) = v;
}

// ---- CSR build (once per launch) ----
__global__ void hist_kernel(const int* __restrict__ ei, int* __restrict__ counts, int e_cnt) {
    int e = blockIdx.x * blockDim.x + threadIdx.x;
    if (e >= e_cnt) return;
    atomicAdd(counts + ei[e_cnt + e], 1);
}

// per-block sums of PADDED degrees
__global__ __launch_bounds__(256) void bsum_kernel(const int* __restrict__ counts,
                                                   int* __restrict__ bsum, int n) {
    __shared__ int s[256];
    int t = threadIdx.x;
    int idx = blockIdx.x * 256 + t;
    s[t] = (idx < n) ? pad8(counts[idx]) : 0;
    __syncthreads();
    for (int off = 128; off > 0; off >>= 1) {
        if (t < off) s[t] += s[t + off];
        __syncthreads();
    }
    if (t == 0) bsum[blockIdx.x] = s[0];
}

__global__ __launch_bounds__(256) void bscan_kernel(const int* __restrict__ bsum,
                                                    int* __restrict__ bpre,
                                                    int* __restrict__ rpp, int nb, int n) {
    __shared__ int s[256];
    int t = threadIdx.x;
    s[t] = (t < nb) ? bsum[t] : 0;
    __syncthreads();
    for (int off = 1; off < 256; off <<= 1) {
        int v = (t >= off) ? s[t - off] : 0;
        __syncthreads();
        s[t] += v;
        __syncthreads();
    }
    bpre[t] = (t == 0) ? 0 : s[t - 1];
    if (t == 255) rpp[n] = s[255];
}

__global__ __launch_bounds__(256) void scan_apply_kernel(const int* __restrict__ counts,
                                                         const int* __restrict__ bpre,
                                                         int* __restrict__ rpp,
                                                         int* __restrict__ cursor, int n) {
    __shared__ int s[256];
    int t = threadIdx.x;
    int idx = blockIdx.x * 256 + t;
    int c = (idx < n) ? pad8(counts[idx]) : 0;
    s[t] = c;
    __syncthreads();
    for (int off = 1; off < 256; off <<= 1) {
        int v = (t >= off) ? s[t - off] : 0;
        __syncthreads();
        s[t] += v;
        __syncthreads();
    }
    if (idx < n) {
        int excl = bpre[blockIdx.x] + s[t] - c;
        rpp[idx] = excl;
        cursor[idx] = excl;
    }
}

// edge fill: ONE u32 scattered store per edge (src | aidx<<17)
__global__ void fill_kernel(const int* __restrict__ ei, const int* __restrict__ ea,
                            int* __restrict__ cursor,
                            unsigned* __restrict__ ep32, int e_cnt) {
    int e = blockIdx.x * blockDim.x + threadIdx.x;
    if (e >= e_cnt) return;
    int dst = ei[e_cnt + e];
    int src = ei[e];
    int aidx = ea[e * 2 + 0] * 3 + ea[e * 2 + 1];   // [0,9)
    int pos = atomicAdd(cursor + dst, 1);
    ep32[pos] = (unsigned)(src & 0x1FFFF) | ((unsigned)aidx << 17);
}

// sequential per node: u32 -> u16 indices, pad to x8 with n, build packed counts
__global__ void convert_kernel(const int* __restrict__ rpp, const int* __restrict__ counts,
                               const unsigned* __restrict__ ep32,
                               unsigned short* __restrict__ ep16,
                               unsigned long long* __restrict__ cnts, int n) {
    int i = blockIdx.x * blockDim.x + threadIdx.x;
    if (i >= n) return;
    const int jb = rpp[i];              // multiple of 8
    const int deg = counts[i];
    const int pe = pad8(deg);
    unsigned long long c = 0ull;
    int j = 0;
    for (; j < deg; ++j) {
        unsigned v = ep32[jb + j];
        ep16[jb + j] = (unsigned short)(v & 0xFFFFu);   // src < 50000 < 2^16
        int a = (int)(v >> 17);
        if (a < 8) c += 1ull << (a * 8);
    }
    for (; j < pe; ++j) ep16[jb + j] = (unsigned short)n;
    cnts[i] = c;
}

// ---- weight fragment pre-pack (bf16, per-lane MFMA B-operand layout) ----
__global__ void frag_prep_kernel(const float* __restrict__ W1,
                                 const float* __restrict__ W2,
                                 unsigned short* __restrict__ w1f,
                                 unsigned short* __restrict__ w2f, int Lnum) {
    int tid = blockIdx.x * blockDim.x + threadIdx.x;
    if (tid >= Lnum * 128 * 64) return;
    int l = tid / 8192;
    int rem = tid % 8192;
    int frag = rem / 64;
    int lane = rem % 64;
    int kg = lane >> 4, cl = lane & 15;
    if (frag < 64) {
        int kk = frag >> 4, tn = frag & 15;
        const float* src = W1 + (size_t)l * D * TWO_D;
        int k0 = kk * 32 + kg * 8, col = tn * 16 + cl;
        unsigned short* dst = w1f + (size_t)l * 32768 + ((size_t)frag * 64 + lane) * 8;
        #pragma unroll
        for (int j = 0; j < 8; ++j) dst[j] = f2bf(src[(size_t)(k0 + j) * TWO_D + col]);
    } else {
        int f2 = frag - 64;
        int kk = f2 >> 3, tn = f2 & 7;
        const float* src = W2 + (size_t)l * TWO_D * D;
        int k0 = kk * 32 + kg * 8, col = tn * 16 + cl;
        unsigned short* dst = w2f + (size_t)l * 32768 + ((size_t)f2 * 64 + lane) * 8;
        #pragma unroll
        for (int j = 0; j < 8; ++j) dst[j] = f2bf(src[(size_t)(k0 + j) * D + col]);
    }
}

// ---- gather: padded branch-free 8-wide loop + FUSED BN of source values ----
// xf(v) = DO_BN ? relu(v*sc+sh) : v. Pad entries read h[n]==0, contributing
// relu(sh) each; corrected by subtracting npad*relu(sh) after the loop.
// Block 0 zeroes stats_cur (for this layer's MLP).
template<int DO_BN>
__global__ __launch_bounds__(256) void gather_kernel(
    const unsigned short* __restrict__ hbf,
    const float* __restrict__ ee0_l, const float* __restrict__ ee1_l,
    const float* __restrict__ stats_prev,
    const float* __restrict__ gamma_p, const float* __restrict__ beta_p,
    float inv_n,
    const int* __restrict__ rpp, const int* __restrict__ counts,
    const unsigned long long* __restrict__ cnts,
    const unsigned short* __restrict__ ep,
    unsigned short* __restrict__ aggrbf, float* __restrict__ stats_cur, int n) {

    __shared__ float cee[16 * D];
    __shared__ float sbn[2 * D];
    const int t = threadIdx.x;
    if (blockIdx.x == 0) stats_cur[t] = 0.f;
    for (int i = t; i < 16 * D; i += 256) {
        int r = i >> 7, d = i & 127;
        cee[i] = (r < 15) ? ee0_l[(r / 3) * D + d] + ee1_l[(r % 3) * D + d]
                          : ee0_l[4 * D + d] + ee1_l[d];
    }
    if (DO_BN && t < 128) {
        float mean = stats_prev[t] * inv_n;
        float var  = stats_prev[128 + t] * inv_n - mean * mean;
        float sc = gamma_p[t] * rsqrtf(var + BN_EPS);
        sbn[t] = sc;
        sbn[128 + t] = beta_p[t] - mean * sc;
    }
    __syncthreads();

    int node = blockIdx.x * 8 + (t >> 5);
    if (node >= n) return;
    int d0 = (t & 31) << 2;

    float4 sc = make_float4(1.f, 1.f, 1.f, 1.f);
    float4 sh = make_float4(0.f, 0.f, 0.f, 0.f);
    float4 rsh = make_float4(0.f, 0.f, 0.f, 0.f);
    if (DO_BN) {
        sc = *reinterpret_cast<const float4*>(sbn + d0);
        sh = *reinterpret_cast<const float4*>(sbn + 128 + d0);
        rsh = make_float4(relu_f(sh.x), relu_f(sh.y), relu_f(sh.z), relu_f(sh.w));
    }

    const int jb = rpp[node];
    const int deg = counts[node];
    const unsigned long long c0 = cnts[node];
    const int nch = pad8(deg) >> 3;

    float ax, ay, az, aw;
    {
        const float4 cs = *reinterpret_cast<const float4*>(cee + 15 * D + d0);
        uint2 hv = *reinterpret_cast<const uint2*>(hbf + (size_t)node * D + d0);
        if (DO_BN) {
            ax = relu_f(bf2f(hv.x & 0xffffu) * sc.x + sh.x) + cs.x;
            ay = relu_f(bf2f(hv.x >> 16)     * sc.y + sh.y) + cs.y;
            az = relu_f(bf2f(hv.y & 0xffffu) * sc.z + sh.z) + cs.z;
            aw = relu_f(bf2f(hv.y >> 16)     * sc.w + sh.w) + cs.w;
        } else {
            ax = bf2f(hv.x & 0xffffu) + cs.x;
            ay = bf2f(hv.x >> 16)     + cs.y;
            az = bf2f(hv.y & 0xffffu) + cs.z;
            aw = bf2f(hv.y >> 16)     + cs.w;
        }
    }

    // edge-embedding contributions from precomputed counts
    int csum = 0;
    #pragma unroll
    for (int a = 0; a < 8; ++a) {
        int fc = (int)((c0 >> (a * 8)) & 0xFFull);
        csum += fc;
        float f = (float)fc;
        const float4 ev = *reinterpret_cast<const float4*>(cee + a * D + d0);
        ax += f * ev.x; ay += f * ev.y; az += f * ev.z; aw += f * ev.w;
    }
    {
        float f = (float)(deg - csum);     // cnt for aidx == 8
        const float4 ev = *reinterpret_cast<const float4*>(cee + 8 * D + d0);
        ax += f * ev.x; ay += f * ev.y; az += f * ev.z; aw += f * ev.w;
    }

#define ROWLD(s_) (*reinterpret_cast<const uint2*>(hbf + (size_t)(s_) * D + d0))
#define EACC(sv) do { \
        if (DO_BN) { \
            ax += relu_f(bf2f((sv).x & 0xffffu) * sc.x + sh.x); \
            ay += relu_f(bf2f((sv).x >> 16)     * sc.y + sh.y); \
            az += relu_f(bf2f((sv).y & 0xffffu) * sc.z + sh.z); \
            aw += relu_f(bf2f((sv).y >> 16)     * sc.w + sh.w); \
        } else { \
            ax += bf2f((sv).x & 0xffffu); ay += bf2f((sv).x >> 16); \
            az += bf2f((sv).y & 0xffffu); aw += bf2f((sv).y >> 16); \
        } } while (0)
#define PROC(iv) do { \
        const uint2 s0 = ROWLD((iv).x & 0xFFFFu), s1 = ROWLD((iv).x >> 16); \
        const uint2 s2 = ROWLD((iv).y & 0xFFFFu), s3 = ROWLD((iv).y >> 16); \
        const uint2 s4 = ROWLD((iv).z & 0xFFFFu), s5 = ROWLD((iv).z >> 16); \
        const uint2 s6 = ROWLD((iv).w & 0xFFFFu), s7 = ROWLD((iv).w >> 16); \
        EACC(s0); EACC(s1); EACC(s2); EACC(s3); \
        EACC(s4); EACC(s5); EACC(s6); EACC(s7); } while (0)

    if (nch) {
        uint4 iv = *reinterpret_cast<const uint4*>(ep + jb);
        for (int c = 1; c < nch; ++c) {
            uint4 nx = *reinterpret_cast<const uint4*>(ep + jb + 8 * c);
            PROC(iv);
            iv = nx;
        }
        PROC(iv);
    }
#undef ROWLD
#undef EACC
#undef PROC

    if (DO_BN) {
        float np = (float)(pad8(deg) - deg);   // pads contributed relu(sh) each
        ax -= np * rsh.x; ay -= np * rsh.y; az -= np * rsh.z; aw -= np * rsh.w;
    }

    uint2 o;
    o.x = pack2(ax, ay);
    o.y = pack2(az, aw);
    *reinterpret_cast<uint2*>(aggrbf + (size_t)node * D + d0) = o;
}

// ---- MFMA fused MLP, paired 32-row tiles (R6 structure) ----
// final_f32: write f32 to outf; else write bf16 IN-PLACE to aggrbf.
__global__ __launch_bounds__(256) void mlp_mfma_kernel(
    unsigned short* __restrict__ aggrbf,
    const bf16x8* __restrict__ w1f, const bf16x8* __restrict__ w2f,
    const float* __restrict__ b1l, const float* __restrict__ b2l,
    float* __restrict__ outf, float* __restrict__ stats, int n, int final_f32) {

    __shared__ unsigned short hid[32 * TWO_D];   // 16 KB, XOR-swizzled
    __shared__ float sred[256];

    const int wave = threadIdx.x >> 6;
    const int lane = threadIdx.x & 63;
    const int arow = lane & 15;
    const int kgrp = lane >> 4;

    bf16x8 W1[4][4];
    #pragma unroll
    for (int kk = 0; kk < 4; ++kk)
        #pragma unroll
        for (int t = 0; t < 4; ++t)
            W1[kk][t] = w1f[(kk * 16 + wave * 4 + t) * 64 + lane];
    bf16x8 W2[8][2];
    #pragma unroll
    for (int kk = 0; kk < 8; ++kk)
        #pragma unroll
        for (int t = 0; t < 2; ++t)
            W2[kk][t] = w2f[(kk * 8 + wave * 2 + t) * 64 + lane];

    float b1v[4], b2v[2];
    #pragma unroll
    for (int t = 0; t < 4; ++t) b1v[t] = b1l[wave * 64 + t * 16 + arow];
    #pragma unroll
    for (int t = 0; t < 2; ++t) b2v[t] = b2l[wave * 32 + t * 16 + arow];

    float ps[2] = {0.f, 0.f}, pq[2] = {0.f, 0.f};

    const int tiles = n >> 4;            // n % 16 == 0
    const int npair = (tiles + 1) >> 1;
    for (int p = blockIdx.x; p < npair; p += gridDim.x) {
        const int t0i = 2 * p, t1i = 2 * p + 1;
        const bool has1 = (t1i < tiles);
        const size_t r0 = (size_t)t0i * 16, r1 = (size_t)t1i * 16;

        bf16x8 a0[4], a1[4];
        #pragma unroll
        for (int kk = 0; kk < 4; ++kk)
            a0[kk] = *reinterpret_cast<const bf16x8*>(
                aggrbf + (r0 + arow) * D + kk * 32 + kgrp * 8);
        if (has1) {
            #pragma unroll
            for (int kk = 0; kk < 4; ++kk)
                a1[kk] = *reinterpret_cast<const bf16x8*>(
                    aggrbf + (r1 + arow) * D + kk * 32 + kgrp * 8);
        }

        f32x4 acc1[4];
        #pragma unroll
        for (int t = 0; t < 4; ++t) acc1[t] = (f32x4){0.f, 0.f, 0.f, 0.f};
        #pragma unroll
        for (int kk = 0; kk < 4; ++kk)
            #pragma unroll
            for (int t = 0; t < 4; ++t)
                acc1[t] = __builtin_amdgcn_mfma_f32_16x16x32_bf16(a0[kk], W1[kk][t], acc1[t], 0, 0, 0);

        __syncthreads();
        #pragma unroll
        for (int t = 0; t < 4; ++t) {
            const int cc = wave * 64 + t * 16 + arow;
            #pragma unroll
            for (int r = 0; r < 4; ++r) {
                const int rr = kgrp * 4 + r;
                hid[(rr * TWO_D + cc) ^ ((rr & 7) << 3)] = f2bf(relu_f(acc1[t][r] + b1v[t]));
            }
        }
        if (has1) {
            #pragma unroll
            for (int t = 0; t < 4; ++t) acc1[t] = (f32x4){0.f, 0.f, 0.f, 0.f};
            #pragma unroll
            for (int kk = 0; kk < 4; ++kk)
                #pragma unroll
                for (int t = 0; t < 4; ++t)
                    acc1[t] = __builtin_amdgcn_mfma_f32_16x16x32_bf16(a1[kk], W1[kk][t], acc1[t], 0, 0, 0);
            #pragma unroll
            for (int t = 0; t < 4; ++t) {
                const int cc = wave * 64 + t * 16 + arow;
                #pragma unroll
                for (int r = 0; r < 4; ++r) {
                    const int rr = 16 + kgrp * 4 + r;
                    hid[(rr * TWO_D + cc) ^ ((rr & 7) << 3)] = f2bf(relu_f(acc1[t][r] + b1v[t]));
                }
            }
        }
        __syncthreads();

        {
            f32x4 acc2[2];
            #pragma unroll
            for (int t = 0; t < 2; ++t) acc2[t] = (f32x4){0.f, 0.f, 0.f, 0.f};
            #pragma unroll
            for (int kk = 0; kk < 8; ++kk) {
                bf16x8 a2 = *reinterpret_cast<const bf16x8*>(
                    hid + ((arow * TWO_D + kk * 32 + kgrp * 8) ^ ((arow & 7) << 3)));
                #pragma unroll
                for (int t = 0; t < 2; ++t)
                    acc2[t] = __builtin_amdgcn_mfma_f32_16x16x32_bf16(a2, W2[kk][t], acc2[t], 0, 0, 0);
            }
            #pragma unroll
            for (int t = 0; t < 2; ++t) {
                const int col = wave * 32 + t * 16 + arow;
                #pragma unroll
                for (int r = 0; r < 4; ++r) {
                    float v = acc2[t][r] + b2v[t];
                    if (final_f32) outf[(r0 + kgrp * 4 + r) * D + col] = v;
                    else           aggrbf[(r0 + kgrp * 4 + r) * D + col] = f2bf(v);
                    ps[t] += v; pq[t] += v * v;
                }
            }
        }
        if (has1) {
            f32x4 acc2[2];
            #pragma unroll
            for (int t = 0; t < 2; ++t) acc2[t] = (f32x4){0.f, 0.f, 0.f, 0.f};
            #pragma unroll
            for (int kk = 0; kk < 8; ++kk) {
                bf16x8 a2 = *reinterpret_cast<const bf16x8*>(
                    hid + (((16 + arow) * TWO_D + kk * 32 + kgrp * 8) ^ ((arow & 7) << 3)));
                #pragma unroll
                for (int t = 0; t < 2; ++t)
                    acc2[t] = __builtin_amdgcn_mfma_f32_16x16x32_bf16(a2, W2[kk][t], acc2[t], 0, 0, 0);
            }
            #pragma unroll
            for (int t = 0; t < 2; ++t) {
                const int col = wave * 32 + t * 16 + arow;
                #pragma unroll
                for (int r = 0; r < 4; ++r) {
                    float v = acc2[t][r] + b2v[t];
                    if (final_f32) outf[(r1 + kgrp * 4 + r) * D + col] = v;
                    else           aggrbf[(r1 + kgrp * 4 + r) * D + col] = f2bf(v);
                    ps[t] += v; pq[t] += v * v;
                }
            }
        }
    }

    sred[threadIdx.x] = 0.f;
    __syncthreads();
    #pragma unroll
    for (int t = 0; t < 2; ++t) {
        const int col = wave * 32 + t * 16 + arow;
        atomicAdd(sred + col, ps[t]);
        atomicAdd(sred + 128 + col, pq[t]);
    }
    __syncthreads();
    unsafeAtomicAdd(stats + threadIdx.x, sred[threadIdx.x]);
}

// final: d_out = out*sc+sh (f32, no relu); sc/sh from stats per block
__global__ void bn_apply_final_kernel(const float* __restrict__ out,
                                      const float* __restrict__ stats,
                                      const float* __restrict__ gamma_l,
                                      const float* __restrict__ beta_l,
                                      float inv_n,
                                      float* __restrict__ dst, int n) {
    __shared__ float sbn[2 * D];
    int t = threadIdx.x;
    if (t < 128) {
        float mean = stats[t] * inv_n;
        float var  = stats[128 + t] * inv_n - mean * mean;
        float sc = gamma_l[t] * rsqrtf(var + BN_EPS);
        sbn[t] = sc;
        sbn[128 + t] = beta_l[t] - mean * sc;
    }
    __syncthreads();
    int idx = blockIdx.x * blockDim.x + t;
    if (idx >= n * 32) return;
    int d0 = (idx & 31) << 2;
    float4 v  = *reinterpret_cast<const float4*>(out + (size_t)idx * 4);
    float4 sc = *reinterpret_cast<const float4*>(sbn + d0);
    float4 sh = *reinterpret_cast<const float4*>(sbn + 128 + d0);
    *reinterpret_cast<float4*>(dst + (size_t)idx * 4) =
        make_float4(v.x * sc.x + sh.x, v.y * sc.y + sh.y,
                    v.z * sc.z + sh.z, v.w * sc.w + sh.w);
}

extern "C" void kernel_launch(void* const* d_in, const int* in_sizes, int n_in,
                              void* d_out, int out_size, void* d_ws, size_t ws_size,
                              hipStream_t stream) {
    const int*   x     = (const int*)d_in[0];
    const int*   ei    = (const int*)d_in[1];
    const int*   ea    = (const int*)d_in[2];
    const float* aemb0 = (const float*)d_in[3];
    const float* aemb1 = (const float*)d_in[4];
    const float* eemb0 = (const float*)d_in[5];
    const float* eemb1 = (const float*)d_in[6];
    const float* W1    = (const float*)d_in[7];
    const float* b1    = (const float*)d_in[8];
    const float* W2    = (const float*)d_in[9];
    const float* b2    = (const float*)d_in[10];
    const float* gamma = (const float*)d_in[11];
    const float* beta  = (const float*)d_in[12];

    const int n = in_sizes[0] / 2;          // 50000
    const int e = in_sizes[1] / 2;          // 500000
    const int L = in_sizes[8] / TWO_D;      // 3
    const float inv_n = 1.0f / (float)n;

    char* ws = (char*)d_ws;
    float* outb = (float*)ws;                      ws += (size_t)n * D * 4;
    unsigned short* bufA = (unsigned short*)ws;    ws += (size_t)(n + 1) * D * 2;
    unsigned short* bufB = (unsigned short*)ws;    ws += (size_t)(n + 1) * D * 2;
    unsigned short* w1f = (unsigned short*)ws;     ws += (size_t)L * 32768 * 2;
    unsigned short* w2f = (unsigned short*)ws;     ws += (size_t)L * 32768 * 2;
    float* statsA = (float*)ws;                    ws += 256 * 4;
    float* statsB = (float*)ws;                    ws += 256 * 4;
    int* counts  = (int*)ws;                       ws += (size_t)n * 4;
    unsigned long long* cnts = (unsigned long long*)ws;  ws += (size_t)n * 8;
    int* rpp     = (int*)ws;                       ws += (size_t)(n + 4) * 4;
    int* cursor  = (int*)ws;                       ws += (size_t)n * 4;
    int* bsum    = (int*)ws;                       ws += 256 * 4;
    int* bpre    = (int*)ws;                       ws += 256 * 4;
    unsigned* ep32 = (unsigned*)ws;                ws += ((size_t)e + 8 * (size_t)n) * 4;
    unsigned short* ep16 = (unsigned short*)ws;    // padded u16 indices

    const int edge_blocks = (e + 255) / 256;
    const int vec_blocks  = (n * 32 + 255) / 256;
    const int node_blocks = (n + 7) / 8;
    const int nb = (n + 255) / 256;          // 196 <= 256

    hipMemsetAsync(counts, 0, (size_t)n * 4, stream);
    hist_kernel<<<edge_blocks, 256, 0, stream>>>(ei, counts, e);
    bsum_kernel<<<nb, 256, 0, stream>>>(counts, bsum, n);
    bscan_kernel<<<1, 256, 0, stream>>>(bsum, bpre, rpp, nb, n);
    scan_apply_kernel<<<nb, 256, 0, stream>>>(counts, bpre, rpp, cursor, n);
    fill_kernel<<<edge_blocks, 256, 0, stream>>>(ei, ea, cursor, ep32, e);
    convert_kernel<<<nb, 256, 0, stream>>>(rpp, counts, ep32, ep16, cnts, n);
    frag_prep_kernel<<<(L * 128 * 64 + 255) / 256, 256, 0, stream>>>(W1, W2, w1f, w2f, L);
    atom_embed_kernel<<<vec_blocks, 256, 0, stream>>>(x, aemb0, aemb1, bufA, bufB, n);

    for (int l = 0; l < L; ++l) {
        const float* ee0_l = eemb0 + (size_t)l * 5 * D;
        const float* ee1_l = eemb1 + (size_t)l * 3 * D;

        unsigned short* src = (l & 1) ? bufB : bufA;   // prev raw values (pre-BN)
        unsigned short* dst = (l & 1) ? bufA : bufB;   // gather out + mlp in/out
        float* stats_cur  = (l & 1) ? statsB : statsA;
        float* stats_prev = (l & 1) ? statsA : statsB;

        if (l == 0)
            gather_kernel<0><<<node_blocks, 256, 0, stream>>>(
                src, ee0_l, ee1_l, nullptr, nullptr, nullptr, inv_n,
                rpp, counts, cnts, ep16, dst, stats_cur, n);
        else
            gather_kernel<1><<<node_blocks, 256, 0, stream>>>(
                src, ee0_l, ee1_l, stats_prev,
                gamma + (size_t)(l - 1) * D, beta + (size_t)(l - 1) * D, inv_n,
                rpp, counts, cnts, ep16, dst, stats_cur, n);

        mlp_mfma_kernel<<<512, 256, 0, stream>>>(
            dst,
            (const bf16x8*)(w1f + (size_t)l * 32768),
            (const bf16x8*)(w2f + (size_t)l * 32768),
            b1 + (size_t)l * TWO_D, b2 + (size_t)l * D,
            outb, stats_cur, n, (l == L - 1) ? 1 : 0);
    }

    float* stats_last = ((L - 1) & 1) ? statsB : statsA;
    bn_apply_final_kernel<<<vec_blocks, 256, 0, stream>>>(
        outb, stats_last, gamma + (size_t)(L - 1) * D, beta + (size_t)(L - 1) * D,
        inv_n, (float*)d_out, n);
}

// Round 13
// 258.432 us; speedup vs baseline: 1.4579x; 1.0382x over previous
//
#include <hip/hip_runtime.h>

#define D 128
#define TWO_D 256
#define BN_EPS 1e-5f

typedef __attribute__((ext_vector_type(8))) short bf16x8;   // 8 bf16 = 4 VGPR
typedef __attribute__((ext_vector_type(4))) float f32x4;
typedef __attribute__((ext_vector_type(4))) unsigned u32x4; // clang vector (nontemporal-ok)

__device__ __forceinline__ float relu_f(float x) { return x > 0.f ? x : 0.f; }

__device__ __forceinline__ unsigned short f2bf(float f) {   // RTN-even
    unsigned u = __builtin_bit_cast(unsigned, f);
    return (unsigned short)((u + 0x7FFFu + ((u >> 16) & 1u)) >> 16);
}
__device__ __forceinline__ float bf2f(unsigned s) {
    unsigned u = s << 16;
    return __builtin_bit_cast(float, u);
}
__device__ __forceinline__ unsigned pack2(float a, float b) {
    return (unsigned)f2bf(a) | ((unsigned)f2bf(b) << 16);
}

__device__ __forceinline__ int pad8(int d) { return (d + 7) & ~7; }

// h = bf16(emb0[x0]+emb1[x1]); zeroes pad row n of BOTH ping-pong buffers
__global__ void atom_embed_kernel(const int* __restrict__ x,
                                  const float* __restrict__ emb0,
                                  const float* __restrict__ emb1,
                                  unsigned short* __restrict__ bufA,
                                  unsigned short* __restrict__ bufB, int n) {
    if (blockIdx.x == 0 && threadIdx.x < 64)
        reinterpret_cast<unsigned*>(bufA + (size_t)n * D)[threadIdx.x] = 0u;
    if (blockIdx.x == 1 && threadIdx.x < 64)
        reinterpret_cast<unsigned*>(bufB + (size_t)n * D)[threadIdx.x] = 0u;
    int idx = blockIdx.x * blockDim.x + threadIdx.x;
    if (idx >= n * 32) return;
    int node = idx >> 5;
    int d0 = (idx & 31) << 2;
    int i0 = x[node * 2 + 0];
    int i1 = x[node * 2 + 1];
    const float4 a = *reinterpret_cast<const float4*>(emb0 + (size_t)i0 * D + d0);
    const float4 b = *reinterpret_cast<const float4*>(emb1 + (size_t)i1 * D + d0);
    uint2 v;
    v.x = pack2(a.x + b.x, a.y + b.y);
    v.y = pack2(a.z + b.z, a.w + b.w);
    *reinterpret_cast<uint2*>(bufA + (size_t)node * D + d0) = v;
}

// ---- CSR build (once per launch) ----
__global__ void hist_kernel(const int* __restrict__ ei, int* __restrict__ counts, int e_cnt) {
    int e = blockIdx.x * blockDim.x + threadIdx.x;
    if (e >= e_cnt) return;
    atomicAdd(counts + ei[e_cnt + e], 1);
}

// per-block sums of PADDED degrees
__global__ __launch_bounds__(256) void bsum_kernel(const int* __restrict__ counts,
                                                   int* __restrict__ bsum, int n) {
    __shared__ int s[256];
    int t = threadIdx.x;
    int idx = blockIdx.x * 256 + t;
    s[t] = (idx < n) ? pad8(counts[idx]) : 0;
    __syncthreads();
    for (int off = 128; off > 0; off >>= 1) {
        if (t < off) s[t] += s[t + off];
        __syncthreads();
    }
    if (t == 0) bsum[blockIdx.x] = s[0];
}

__global__ __launch_bounds__(256) void bscan_kernel(const int* __restrict__ bsum,
                                                    int* __restrict__ bpre,
                                                    int* __restrict__ rpp, int nb, int n) {
    __shared__ int s[256];
    int t = threadIdx.x;
    s[t] = (t < nb) ? bsum[t] : 0;
    __syncthreads();
    for (int off = 1; off < 256; off <<= 1) {
        int v = (t >= off) ? s[t - off] : 0;
        __syncthreads();
        s[t] += v;
        __syncthreads();
    }
    bpre[t] = (t == 0) ? 0 : s[t - 1];
    if (t == 255) rpp[n] = s[255];
}

__global__ __launch_bounds__(256) void scan_apply_kernel(const int* __restrict__ counts,
                                                         const int* __restrict__ bpre,
                                                         int* __restrict__ rpp,
                                                         int* __restrict__ cursor, int n) {
    __shared__ int s[256];
    int t = threadIdx.x;
    int idx = blockIdx.x * 256 + t;
    int c = (idx < n) ? pad8(counts[idx]) : 0;
    s[t] = c;
    __syncthreads();
    for (int off = 1; off < 256; off <<= 1) {
        int v = (t >= off) ? s[t - off] : 0;
        __syncthreads();
        s[t] += v;
        __syncthreads();
    }
    if (idx < n) {
        int excl = bpre[blockIdx.x] + s[t] - c;
        rpp[idx] = excl;
        cursor[idx] = excl;
    }
}

// edge fill: ONE u32 scattered store per edge (src | aidx<<17)
__global__ void fill_kernel(const int* __restrict__ ei, const int* __restrict__ ea,
                            int* __restrict__ cursor,
                            unsigned* __restrict__ ep32, int e_cnt) {
    int e = blockIdx.x * blockDim.x + threadIdx.x;
    if (e >= e_cnt) return;
    int dst = ei[e_cnt + e];
    int src = ei[e];
    int aidx = ea[e * 2 + 0] * 3 + ea[e * 2 + 1];   // [0,9)
    int pos = atomicAdd(cursor + dst, 1);
    ep32[pos] = (unsigned)(src & 0x1FFFF) | ((unsigned)aidx << 17);
}

// sequential per node: u32 -> u16 indices, pad to x8 with n, build packed counts
__global__ void convert_kernel(const int* __restrict__ rpp, const int* __restrict__ counts,
                               const unsigned* __restrict__ ep32,
                               unsigned short* __restrict__ ep16,
                               unsigned long long* __restrict__ cnts, int n) {
    int i = blockIdx.x * blockDim.x + threadIdx.x;
    if (i >= n) return;
    const int jb = rpp[i];              // multiple of 8
    const int deg = counts[i];
    const int pe = pad8(deg);
    unsigned long long c = 0ull;
    int j = 0;
    for (; j < deg; ++j) {
        unsigned v = ep32[jb + j];
        ep16[jb + j] = (unsigned short)(v & 0xFFFFu);   // src < 50000 < 2^16
        int a = (int)(v >> 17);
        if (a < 8) c += 1ull << (a * 8);
    }
    for (; j < pe; ++j) ep16[jb + j] = (unsigned short)n;
    cnts[i] = c;
}

// ---- weight fragment pre-pack (bf16, per-lane MFMA B-operand layout) ----
__global__ void frag_prep_kernel(const float* __restrict__ W1,
                                 const float* __restrict__ W2,
                                 unsigned short* __restrict__ w1f,
                                 unsigned short* __restrict__ w2f, int Lnum) {
    int tid = blockIdx.x * blockDim.x + threadIdx.x;
    if (tid >= Lnum * 128 * 64) return;
    int l = tid / 8192;
    int rem = tid % 8192;
    int frag = rem / 64;
    int lane = rem % 64;
    int kg = lane >> 4, cl = lane & 15;
    if (frag < 64) {
        int kk = frag >> 4, tn = frag & 15;
        const float* src = W1 + (size_t)l * D * TWO_D;
        int k0 = kk * 32 + kg * 8, col = tn * 16 + cl;
        unsigned short* dst = w1f + (size_t)l * 32768 + ((size_t)frag * 64 + lane) * 8;
        #pragma unroll
        for (int j = 0; j < 8; ++j) dst[j] = f2bf(src[(size_t)(k0 + j) * TWO_D + col]);
    } else {
        int f2 = frag - 64;
        int kk = f2 >> 3, tn = f2 & 7;
        const float* src = W2 + (size_t)l * TWO_D * D;
        int k0 = kk * 32 + kg * 8, col = tn * 16 + cl;
        unsigned short* dst = w2f + (size_t)l * 32768 + ((size_t)f2 * 64 + lane) * 8;
        #pragma unroll
        for (int j = 0; j < 8; ++j) dst[j] = f2bf(src[(size_t)(k0 + j) * D + col]);
    }
}

// ---- gather v2: 16 lanes/node, uint4 (16B) row loads, padded 8-wide ILP ----
// Each 16-lane group owns one node; lane lq covers elements [lq*8, lq*8+8).
// Per edge: ONE 16B load per lane (half the VMEM instructions of v1).
// xf(v) = DO_BN ? relu(v*sc+sh) : v ; pads read h[n]==0 -> contribute
// relu(sh), corrected by -npad*relu(sh). Block 0 zeroes stats_cur.
// aggr written with nontemporal stores (keep L2 for the h table).
template<int DO_BN>
__global__ __launch_bounds__(256) void gather_kernel(
    const unsigned short* __restrict__ hbf,
    const float* __restrict__ ee0_l, const float* __restrict__ ee1_l,
    const float* __restrict__ stats_prev,
    const float* __restrict__ gamma_p, const float* __restrict__ beta_p,
    float inv_n,
    const int* __restrict__ rpp, const int* __restrict__ counts,
    const unsigned long long* __restrict__ cnts,
    const unsigned short* __restrict__ ep,
    unsigned short* __restrict__ aggrbf, float* __restrict__ stats_cur, int n) {

    __shared__ float cee[16 * D];
    __shared__ float sbn[2 * D];
    const int t = threadIdx.x;
    if (blockIdx.x == 0) stats_cur[t] = 0.f;
    for (int i = t; i < 16 * D; i += 256) {
        int r = i >> 7, d = i & 127;
        cee[i] = (r < 15) ? ee0_l[(r / 3) * D + d] + ee1_l[(r % 3) * D + d]
                          : ee0_l[4 * D + d] + ee1_l[d];
    }
    if (DO_BN && t < 128) {
        float mean = stats_prev[t] * inv_n;
        float var  = stats_prev[128 + t] * inv_n - mean * mean;
        float sc = gamma_p[t] * rsqrtf(var + BN_EPS);
        sbn[t] = sc;
        sbn[128 + t] = beta_p[t] - mean * sc;
    }
    __syncthreads();

    int node = blockIdx.x * 16 + (t >> 4);
    if (node >= n) return;
    const int d0 = (t & 15) << 3;     // 8 elements per lane

    float sc8[8], sh8[8];
    if (DO_BN) {
        #pragma unroll
        for (int j = 0; j < 8; ++j) { sc8[j] = sbn[d0 + j]; sh8[j] = sbn[128 + d0 + j]; }
    }

    const int jb = rpp[node];
    const int deg = counts[node];
    const unsigned long long c0 = cnts[node];
    const int nch = pad8(deg) >> 3;

    float acc[8];
    {
        u32x4 hv = *reinterpret_cast<const u32x4*>(hbf + (size_t)node * D + d0);
        #pragma unroll
        for (int j = 0; j < 4; ++j) {
            float lo = bf2f(hv[j] & 0xffffu), hi = bf2f(hv[j] >> 16);
            if (DO_BN) {
                acc[2 * j]     = relu_f(lo * sc8[2 * j]     + sh8[2 * j]);
                acc[2 * j + 1] = relu_f(hi * sc8[2 * j + 1] + sh8[2 * j + 1]);
            } else {
                acc[2 * j] = lo; acc[2 * j + 1] = hi;
            }
        }
        #pragma unroll
        for (int j = 0; j < 8; ++j) acc[j] += cee[15 * D + d0 + j];
    }

    // edge-embedding contributions from precomputed counts
    int csum = 0;
    #pragma unroll
    for (int a = 0; a < 8; ++a) {
        int fc = (int)((c0 >> (a * 8)) & 0xFFull);
        csum += fc;
        float f = (float)fc;
        #pragma unroll
        for (int j = 0; j < 8; ++j) acc[j] += f * cee[a * D + d0 + j];
    }
    {
        float f = (float)(deg - csum);     // cnt for aidx == 8
        #pragma unroll
        for (int j = 0; j < 8; ++j) acc[j] += f * cee[8 * D + d0 + j];
    }

#define ROWLD(s_) (*reinterpret_cast<const u32x4*>(hbf + (size_t)(s_) * D + d0))
#define EACC(q) do { \
        _Pragma("unroll") \
        for (int j_ = 0; j_ < 4; ++j_) { \
            float lo_ = bf2f((q)[j_] & 0xffffu), hi_ = bf2f((q)[j_] >> 16); \
            if (DO_BN) { \
                acc[2 * j_]     += relu_f(lo_ * sc8[2 * j_]     + sh8[2 * j_]); \
                acc[2 * j_ + 1] += relu_f(hi_ * sc8[2 * j_ + 1] + sh8[2 * j_ + 1]); \
            } else { \
                acc[2 * j_] += lo_; acc[2 * j_ + 1] += hi_; \
            } \
        } } while (0)
#define PROC(iv) do { \
        const u32x4 r0_ = ROWLD((iv).x & 0xFFFFu), r1_ = ROWLD((iv).x >> 16); \
        const u32x4 r2_ = ROWLD((iv).y & 0xFFFFu), r3_ = ROWLD((iv).y >> 16); \
        const u32x4 r4_ = ROWLD((iv).z & 0xFFFFu), r5_ = ROWLD((iv).z >> 16); \
        const u32x4 r6_ = ROWLD((iv).w & 0xFFFFu), r7_ = ROWLD((iv).w >> 16); \
        EACC(r0_); EACC(r1_); EACC(r2_); EACC(r3_); \
        EACC(r4_); EACC(r5_); EACC(r6_); EACC(r7_); } while (0)

    if (nch) {
        uint4 iv = *reinterpret_cast<const uint4*>(ep + jb);
        for (int c = 1; c < nch; ++c) {
            uint4 nx = *reinterpret_cast<const uint4*>(ep + jb + 8 * c);
            PROC(iv);
            iv = nx;
        }
        PROC(iv);
    }
#undef ROWLD
#undef EACC
#undef PROC

    if (DO_BN) {
        float np = (float)(pad8(deg) - deg);   // pads contributed relu(sh) each
        #pragma unroll
        for (int j = 0; j < 8; ++j) acc[j] -= np * relu_f(sh8[j]);
    }

    u32x4 o;
    o[0] = pack2(acc[0], acc[1]);
    o[1] = pack2(acc[2], acc[3]);
    o[2] = pack2(acc[4], acc[5]);
    o[3] = pack2(acc[6], acc[7]);
    __builtin_nontemporal_store(o, reinterpret_cast<u32x4*>(aggrbf + (size_t)node * D + d0));
}

// ---- MFMA fused MLP, paired 32-row tiles (R6 structure) ----
// final_f32: write f32 to outf; else write bf16 IN-PLACE to aggrbf.
__global__ __launch_bounds__(256) void mlp_mfma_kernel(
    unsigned short* __restrict__ aggrbf,
    const bf16x8* __restrict__ w1f, const bf16x8* __restrict__ w2f,
    const float* __restrict__ b1l, const float* __restrict__ b2l,
    float* __restrict__ outf, float* __restrict__ stats, int n, int final_f32) {

    __shared__ unsigned short hid[32 * TWO_D];   // 16 KB, XOR-swizzled
    __shared__ float sred[256];

    const int wave = threadIdx.x >> 6;
    const int lane = threadIdx.x & 63;
    const int arow = lane & 15;
    const int kgrp = lane >> 4;

    bf16x8 W1[4][4];
    #pragma unroll
    for (int kk = 0; kk < 4; ++kk)
        #pragma unroll
        for (int t = 0; t < 4; ++t)
            W1[kk][t] = w1f[(kk * 16 + wave * 4 + t) * 64 + lane];
    bf16x8 W2[8][2];
    #pragma unroll
    for (int kk = 0; kk < 8; ++kk)
        #pragma unroll
        for (int t = 0; t < 2; ++t)
            W2[kk][t] = w2f[(kk * 8 + wave * 2 + t) * 64 + lane];

    float b1v[4], b2v[2];
    #pragma unroll
    for (int t = 0; t < 4; ++t) b1v[t] = b1l[wave * 64 + t * 16 + arow];
    #pragma unroll
    for (int t = 0; t < 2; ++t) b2v[t] = b2l[wave * 32 + t * 16 + arow];

    float ps[2] = {0.f, 0.f}, pq[2] = {0.f, 0.f};

    const int tiles = n >> 4;            // n % 16 == 0
    const int npair = (tiles + 1) >> 1;
    for (int p = blockIdx.x; p < npair; p += gridDim.x) {
        const int t0i = 2 * p, t1i = 2 * p + 1;
        const bool has1 = (t1i < tiles);
        const size_t r0 = (size_t)t0i * 16, r1 = (size_t)t1i * 16;

        bf16x8 a0[4], a1[4];
        #pragma unroll
        for (int kk = 0; kk < 4; ++kk)
            a0[kk] = *reinterpret_cast<const bf16x8*>(
                aggrbf + (r0 + arow) * D + kk * 32 + kgrp * 8);
        if (has1) {
            #pragma unroll
            for (int kk = 0; kk < 4; ++kk)
                a1[kk] = *reinterpret_cast<const bf16x8*>(
                    aggrbf + (r1 + arow) * D + kk * 32 + kgrp * 8);
        }

        f32x4 acc1[4];
        #pragma unroll
        for (int t = 0; t < 4; ++t) acc1[t] = (f32x4){0.f, 0.f, 0.f, 0.f};
        #pragma unroll
        for (int kk = 0; kk < 4; ++kk)
            #pragma unroll
            for (int t = 0; t < 4; ++t)
                acc1[t] = __builtin_amdgcn_mfma_f32_16x16x32_bf16(a0[kk], W1[kk][t], acc1[t], 0, 0, 0);

        __syncthreads();
        #pragma unroll
        for (int t = 0; t < 4; ++t) {
            const int cc = wave * 64 + t * 16 + arow;
            #pragma unroll
            for (int r = 0; r < 4; ++r) {
                const int rr = kgrp * 4 + r;
                hid[(rr * TWO_D + cc) ^ ((rr & 7) << 3)] = f2bf(relu_f(acc1[t][r] + b1v[t]));
            }
        }
        if (has1) {
            #pragma unroll
            for (int t = 0; t < 4; ++t) acc1[t] = (f32x4){0.f, 0.f, 0.f, 0.f};
            #pragma unroll
            for (int kk = 0; kk < 4; ++kk)
                #pragma unroll
                for (int t = 0; t < 4; ++t)
                    acc1[t] = __builtin_amdgcn_mfma_f32_16x16x32_bf16(a1[kk], W1[kk][t], acc1[t], 0, 0, 0);
            #pragma unroll
            for (int t = 0; t < 4; ++t) {
                const int cc = wave * 64 + t * 16 + arow;
                #pragma unroll
                for (int r = 0; r < 4; ++r) {
                    const int rr = 16 + kgrp * 4 + r;
                    hid[(rr * TWO_D + cc) ^ ((rr & 7) << 3)] = f2bf(relu_f(acc1[t][r] + b1v[t]));
                }
            }
        }
        __syncthreads();

        {
            f32x4 acc2[2];
            #pragma unroll
            for (int t = 0; t < 2; ++t) acc2[t] = (f32x4){0.f, 0.f, 0.f, 0.f};
            #pragma unroll
            for (int kk = 0; kk < 8; ++kk) {
                bf16x8 a2 = *reinterpret_cast<const bf16x8*>(
                    hid + ((arow * TWO_D + kk * 32 + kgrp * 8) ^ ((arow & 7) << 3)));
                #pragma unroll
                for (int t = 0; t < 2; ++t)
                    acc2[t] = __builtin_amdgcn_mfma_f32_16x16x32_bf16(a2, W2[kk][t], acc2[t], 0, 0, 0);
            }
            #pragma unroll
            for (int t = 0; t < 2; ++t) {
                const int col = wave * 32 + t * 16 + arow;
                #pragma unroll
                for (int r = 0; r < 4; ++r) {
                    float v = acc2[t][r] + b2v[t];
                    if (final_f32) outf[(r0 + kgrp * 4 + r) * D + col] = v;
                    else           aggrbf[(r0 + kgrp * 4 + r) * D + col] = f2bf(v);
                    ps[t] += v; pq[t] += v * v;
                }
            }
        }
        if (has1) {
            f32x4 acc2[2];
            #pragma unroll
            for (int t = 0; t < 2; ++t) acc2[t] = (f32x4){0.f, 0.f, 0.f, 0.f};
            #pragma unroll
            for (int kk = 0; kk < 8; ++kk) {
                bf16x8 a2 = *reinterpret_cast<const bf16x8*>(
                    hid + (((16 + arow) * TWO_D + kk * 32 + kgrp * 8) ^ ((arow & 7) << 3)));
                #pragma unroll
                for (int t = 0; t < 2; ++t)
                    acc2[t] = __builtin_amdgcn_mfma_f32_16x16x32_bf16(a2, W2[kk][t], acc2[t], 0, 0, 0);
            }
            #pragma unroll
            for (int t = 0; t < 2; ++t) {
                const int col = wave * 32 + t * 16 + arow;
                #pragma unroll
                for (int r = 0; r < 4; ++r) {
                    float v = acc2[t][r] + b2v[t];
                    if (final_f32) outf[(r1 + kgrp * 4 + r) * D + col] = v;
                    else           aggrbf[(r1 + kgrp * 4 + r) * D + col] = f2bf(v);
                    ps[t] += v; pq[t] += v * v;
                }
            }
        }
    }

    sred[threadIdx.x] = 0.f;
    __syncthreads();
    #pragma unroll
    for (int t = 0; t < 2; ++t) {
        const int col = wave * 32 + t * 16 + arow;
        atomicAdd(sred + col, ps[t]);
        atomicAdd(sred + 128 + col, pq[t]);
    }
    __syncthreads();
    unsafeAtomicAdd(stats + threadIdx.x, sred[threadIdx.x]);
}

// final: d_out = out*sc+sh (f32, no relu); sc/sh from stats per block
__global__ void bn_apply_final_kernel(const float* __restrict__ out,
                                      const float* __restrict__ stats,
                                      const float* __restrict__ gamma_l,
                                      const float* __restrict__ beta_l,
                                      float inv_n,
                                      float* __restrict__ dst, int n) {
    __shared__ float sbn[2 * D];
    int t = threadIdx.x;
    if (t < 128) {
        float mean = stats[t] * inv_n;
        float var  = stats[128 + t] * inv_n - mean * mean;
        float sc = gamma_l[t] * rsqrtf(var + BN_EPS);
        sbn[t] = sc;
        sbn[128 + t] = beta_l[t] - mean * sc;
    }
    __syncthreads();
    int idx = blockIdx.x * blockDim.x + t;
    if (idx >= n * 32) return;
    int d0 = (idx & 31) << 2;
    float4 v  = *reinterpret_cast<const float4*>(out + (size_t)idx * 4);
    float4 sc = *reinterpret_cast<const float4*>(sbn + d0);
    float4 sh = *reinterpret_cast<const float4*>(sbn + 128 + d0);
    *reinterpret_cast<float4*>(dst + (size_t)idx * 4) =
        make_float4(v.x * sc.x + sh.x, v.y * sc.y + sh.y,
                    v.z * sc.z + sh.z, v.w * sc.w + sh.w);
}

extern "C" void kernel_launch(void* const* d_in, const int* in_sizes, int n_in,
                              void* d_out, int out_size, void* d_ws, size_t ws_size,
                              hipStream_t stream) {
    const int*   x     = (const int*)d_in[0];
    const int*   ei    = (const int*)d_in[1];
    const int*   ea    = (const int*)d_in[2];
    const float* aemb0 = (const float*)d_in[3];
    const float* aemb1 = (const float*)d_in[4];
    const float* eemb0 = (const float*)d_in[5];
    const float* eemb1 = (const float*)d_in[6];
    const float* W1    = (const float*)d_in[7];
    const float* b1    = (const float*)d_in[8];
    const float* W2    = (const float*)d_in[9];
    const float* b2    = (const float*)d_in[10];
    const float* gamma = (const float*)d_in[11];
    const float* beta  = (const float*)d_in[12];

    const int n = in_sizes[0] / 2;          // 50000
    const int e = in_sizes[1] / 2;          // 500000
    const int L = in_sizes[8] / TWO_D;      // 3
    const float inv_n = 1.0f / (float)n;

    char* ws = (char*)d_ws;
    float* outb = (float*)ws;                      ws += (size_t)n * D * 4;
    unsigned short* bufA = (unsigned short*)ws;    ws += (size_t)(n + 1) * D * 2;
    unsigned short* bufB = (unsigned short*)ws;    ws += (size_t)(n + 1) * D * 2;
    unsigned short* w1f = (unsigned short*)ws;     ws += (size_t)L * 32768 * 2;
    unsigned short* w2f = (unsigned short*)ws;     ws += (size_t)L * 32768 * 2;
    float* statsA = (float*)ws;                    ws += 256 * 4;
    float* statsB = (float*)ws;                    ws += 256 * 4;
    int* counts  = (int*)ws;                       ws += (size_t)n * 4;
    unsigned long long* cnts = (unsigned long long*)ws;  ws += (size_t)n * 8;
    int* rpp     = (int*)ws;                       ws += (size_t)(n + 4) * 4;
    int* cursor  = (int*)ws;                       ws += (size_t)n * 4;
    int* bsum    = (int*)ws;                       ws += 256 * 4;
    int* bpre    = (int*)ws;                       ws += 256 * 4;
    unsigned* ep32 = (unsigned*)ws;                ws += ((size_t)e + 8 * (size_t)n) * 4;
    unsigned short* ep16 = (unsigned short*)ws;    // padded u16 indices

    const int edge_blocks = (e + 255) / 256;
    const int vec_blocks  = (n * 32 + 255) / 256;
    const int node_blocks = (n + 15) / 16;
    const int nb = (n + 255) / 256;          // 196 <= 256

    hipMemsetAsync(counts, 0, (size_t)n * 4, stream);
    hist_kernel<<<edge_blocks, 256, 0, stream>>>(ei, counts, e);
    bsum_kernel<<<nb, 256, 0, stream>>>(counts, bsum, n);
    bscan_kernel<<<1, 256, 0, stream>>>(bsum, bpre, rpp, nb, n);
    scan_apply_kernel<<<nb, 256, 0, stream>>>(counts, bpre, rpp, cursor, n);
    fill_kernel<<<edge_blocks, 256, 0, stream>>>(ei, ea, cursor, ep32, e);
    convert_kernel<<<nb, 256, 0, stream>>>(rpp, counts, ep32, ep16, cnts, n);
    frag_prep_kernel<<<(L * 128 * 64 + 255) / 256, 256, 0, stream>>>(W1, W2, w1f, w2f, L);
    atom_embed_kernel<<<vec_blocks, 256, 0, stream>>>(x, aemb0, aemb1, bufA, bufB, n);

    for (int l = 0; l < L; ++l) {
        const float* ee0_l = eemb0 + (size_t)l * 5 * D;
        const float* ee1_l = eemb1 + (size_t)l * 3 * D;

        unsigned short* src = (l & 1) ? bufB : bufA;   // prev raw values (pre-BN)
        unsigned short* dst = (l & 1) ? bufA : bufB;   // gather out + mlp in/out
        float* stats_cur  = (l & 1) ? statsB : statsA;
        float* stats_prev = (l & 1) ? statsA : statsB;

        if (l == 0)
            gather_kernel<0><<<node_blocks, 256, 0, stream>>>(
                src, ee0_l, ee1_l, nullptr, nullptr, nullptr, inv_n,
                rpp, counts, cnts, ep16, dst, stats_cur, n);
        else
            gather_kernel<1><<<node_blocks, 256, 0, stream>>>(
                src, ee0_l, ee1_l, stats_prev,
                gamma + (size_t)(l - 1) * D, beta + (size_t)(l - 1) * D, inv_n,
                rpp, counts, cnts, ep16, dst, stats_cur, n);

        mlp_mfma_kernel<<<512, 256, 0, stream>>>(
            dst,
            (const bf16x8*)(w1f + (size_t)l * 32768),
            (const bf16x8*)(w2f + (size_t)l * 32768),
            b1 + (size_t)l * TWO_D, b2 + (size_t)l * D,
            outb, stats_cur, n, (l == L - 1) ? 1 : 0);
    }

    float* stats_last = ((L - 1) & 1) ? statsB : statsA;
    bn_apply_final_kernel<<<vec_blocks, 256, 0, stream>>>(
        outb, stats_last, gamma + (size_t)(L - 1) * D, beta + (size_t)(L - 1) * D,
        inv_n, (float*)d_out, n);
}